// Round 5
// baseline (253.823 us; speedup 1.0000x reference)
//
#include <hip/hip_runtime.h>
#include <hip/hip_bf16.h>

#define H1 8
#define F1 256
#define NEG 0.2f
#define DEGCAP 64   // register path handles deg <= 64 (max deg ~45 here); fallback correct for any deg

// ---------------- CSR build ----------------
__global__ void count_edges(const int* __restrict__ dst_in, int E, int N, int* __restrict__ counts) {
    int i = blockIdx.x * blockDim.x + threadIdx.x;
    int tot = E + N;
    if (i < tot) {
        int d = (i < E) ? dst_in[i] : (i - E);   // self-loops appended
        atomicAdd(&counts[d], 1);
    }
}

// per-block exclusive scan (in-place into counts) + block sums
__global__ void scan_blk(int* __restrict__ counts, int N, int* __restrict__ bsum) {
    __shared__ int tmp[256];
    int tid = threadIdx.x;
    int i = blockIdx.x * 256 + tid;
    int v = (i < N) ? counts[i] : 0;
    tmp[tid] = v;
    __syncthreads();
    for (int off = 1; off < 256; off <<= 1) {
        int u = (tid >= off) ? tmp[tid - off] : 0;
        __syncthreads();
        tmp[tid] += u;
        __syncthreads();
    }
    if (i < N) counts[i] = tmp[tid] - v;        // exclusive within block
    if (tid == 255) bsum[blockIdx.x] = tmp[255];
}

// adds block offsets (computed per-block via LDS tree over bsum) -> rowptr/cursor; block 0 writes rowptr[N]
__global__ void scan_add2(const int* __restrict__ excl, const int* __restrict__ bsum, int nb, int N,
                          int* __restrict__ rowptr, int* __restrict__ cursor) {
    __shared__ int sb[256];
    int tid = threadIdx.x, bid = blockIdx.x;
    int v = 0;
    if (tid < nb && (bid == 0 || tid < bid)) v = bsum[tid];   // bid 0: full sum; else: prefix
    sb[tid] = v;
    __syncthreads();
    for (int off = 128; off; off >>= 1) {
        if (tid < off) sb[tid] += sb[tid + off];
        __syncthreads();
    }
    int s0 = sb[0];
    int boff = (bid == 0) ? 0 : s0;
    if (bid == 0 && tid == 0) rowptr[N] = s0;
    int i = bid * 256 + tid;
    if (i < N) {
        int rp = excl[i] + boff;
        rowptr[i] = rp;
        cursor[i] = rp;
    }
}

__global__ void scatter_edges(const int* __restrict__ src_in, const int* __restrict__ dst_in,
                              int E, int N, int* __restrict__ cursor, int* __restrict__ csr_src) {
    int i = blockIdx.x * blockDim.x + threadIdx.x;
    int tot = E + N;
    if (i < tot) {
        int s, d;
        if (i < E) { s = src_in[i]; d = dst_in[i]; }
        else       { s = i - E;     d = i - E; }
        int pos = atomicAdd(&cursor[d], 1);
        csr_src[pos] = s;
    }
}

// ---------------- layer-1 per-node attention scalars (prep_w fused in) ----------------
// block: 256 thr = 32 nodes x 8 heads
__global__ __launch_bounds__(256) void alpha1(const float* __restrict__ x, const float* __restrict__ W1,
                                              const float* __restrict__ as1, const float* __restrict__ ad1,
                                              float* __restrict__ asrc, float* __restrict__ adst, int N) {
    __shared__ float sws[8 * 33], swd[8 * 33];
    __shared__ float sx[32 * 33];
    int t = threadIdx.x;
    // fold attention vectors through W1: w1s[h][d] = sum_c W1[d, h*32+c]*as1[h,c]
    {
        int h = t >> 5, d = t & 31;
        float s1 = 0.f, d1 = 0.f;
#pragma unroll
        for (int c = 0; c < 32; ++c) {
            float w = W1[d * F1 + h * 32 + c];
            s1 = fmaf(w, as1[h * 32 + c], s1);
            d1 = fmaf(w, ad1[h * 32 + c], d1);
        }
        sws[h * 33 + d] = s1; swd[h * 33 + d] = d1;
    }
    int base = blockIdx.x * 32;
    for (int i = t; i < 1024; i += 256) {
        int r = i >> 5, d = i & 31;
        int n = base + r;
        sx[r * 33 + d] = (n < N) ? x[n * 32 + d] : 0.f;
    }
    __syncthreads();
    int r = t >> 3, h = t & 7;
    float ps = 0.f, pd = 0.f;
#pragma unroll
    for (int d = 0; d < 32; ++d) {
        float xv = sx[r * 33 + d];
        ps = fmaf(xv, sws[h * 33 + d], ps);
        pd = fmaf(xv, swd[h * 33 + d], pd);
    }
    int n = base + r;
    if (n < N) { asrc[n * 8 + h] = ps; adst[n * 8 + h] = pd; }
}

// ---------------- fused layer-1 + layer-2 linear, register/shuffle edition ----------------
// block per node, 256 thr = 8 head-groups x 32 channels. 1 KB LDS, 1 barrier.
__global__ __launch_bounds__(256) void agg1f(
    const float* __restrict__ x, const float* __restrict__ asrc, const float* __restrict__ adst,
    const int* __restrict__ rowptr, const int* __restrict__ csr_src,
    const float* __restrict__ W1, const float* __restrict__ b1,
    const float* __restrict__ W2, const float* __restrict__ as2, const float* __restrict__ ad2,
    float* __restrict__ xh2, float* __restrict__ asrc2, float* __restrict__ adst2, int N) {
    __shared__ float spart[H1][32];
    int node = blockIdx.x;
    int tid = threadIdx.x, h = tid >> 5, lane = tid & 31;
    int beg = rowptr[node];
    int deg = rowptr[node + 1] - beg;
    float adn = adst[node * 8 + h];
    float acc = 0.f;

    if (deg <= DEGCAP) {
        int si0 = 0, si1 = 0;
        float e0 = -1e30f, e1 = -1e30f;
        if (lane < deg) {
            si0 = csr_src[beg + lane];
            e0 = asrc[si0 * 8 + h] + adn;
            e0 = fmaxf(e0, NEG * e0);
        }
        if (32 + lane < deg) {
            si1 = csr_src[beg + 32 + lane];
            e1 = asrc[si1 * 8 + h] + adn;
            e1 = fmaxf(e1, NEG * e1);
        }
        float m = fmaxf(e0, e1);
#pragma unroll
        for (int off = 16; off; off >>= 1) m = fmaxf(m, __shfl_xor(m, off, 32));
        float w0 = (lane < deg) ? __expf(e0 - m) : 0.f;
        float w1 = (32 + lane < deg) ? __expf(e1 - m) : 0.f;
        float dsum = w0 + w1;
#pragma unroll
        for (int off = 16; off; off >>= 1) dsum += __shfl_xor(dsum, off, 32);
        float inv = 1.f / (dsum + 1e-16f);
        int d0 = deg < 32 ? deg : 32;
        for (int i = 0; i < d0; ++i) {
            int s = __shfl(si0, i, 32);
            float a = __shfl(w0, i, 32);
            acc = fmaf(a, x[s * 32 + lane], acc);
        }
        for (int i = 32; i < deg; ++i) {
            int s = __shfl(si1, i - 32, 32);
            float a = __shfl(w1, i - 32, 32);
            acc = fmaf(a, x[s * 32 + lane], acc);
        }
        acc *= inv;
    } else {
        // generic fallback (recompute from global) — correct for any degree
        float m = -1e30f;
        for (int i = lane; i < deg; i += 32) {
            int s = csr_src[beg + i];
            float e = asrc[s * 8 + h] + adn;
            e = fmaxf(e, NEG * e);
            m = fmaxf(m, e);
        }
#pragma unroll
        for (int off = 16; off; off >>= 1) m = fmaxf(m, __shfl_xor(m, off, 32));
        float dsum = 0.f;
        for (int i = lane; i < deg; i += 32) {
            int s = csr_src[beg + i];
            float e = asrc[s * 8 + h] + adn;
            e = fmaxf(e, NEG * e);
            dsum += __expf(e - m);
        }
#pragma unroll
        for (int off = 16; off; off >>= 1) dsum += __shfl_xor(dsum, off, 32);
        float inv = 1.f / (dsum + 1e-16f);
        for (int i = 0; i < deg; ++i) {
            int s = csr_src[beg + i];
            float e = asrc[s * 8 + h] + adn;
            e = fmaxf(e, NEG * e);
            acc = fmaf(__expf(e - m) * inv, x[s * 32 + lane], acc);
        }
    }

    // blockdiag W1 + bias + ReLU via intra-group shuffles (acc lives in lane d)
    float v = 0.f;
#pragma unroll
    for (int d = 0; d < 32; ++d) {
        float ad_ = __shfl(acc, d, 32);
        v = fmaf(ad_, W1[d * F1 + tid], v);
    }
    v += b1[tid];
    v = fmaxf(v, 0.f);

    // fused layer-2 linear: group h holds x2 cols h*32..h*32+31 in regs -> shuffles
    float p = 0.f;
#pragma unroll
    for (int k2 = 0; k2 < 32; ++k2) {
        float xv = __shfl(v, k2, 32);
        p = fmaf(xv, W2[(h * 32 + k2) * 32 + lane], p);
    }
    spart[h][lane] = p;
    __syncthreads();
    if (tid < 32) {
        float o = 0.f;
#pragma unroll
        for (int g2 = 0; g2 < 8; ++g2) o += spart[g2][tid];
        xh2[node * 32 + tid] = o;
        float ps = o * as2[tid], pd = o * ad2[tid];
#pragma unroll
        for (int off = 16; off; off >>= 1) { ps += __shfl_xor(ps, off, 32); pd += __shfl_xor(pd, off, 32); }
        if (tid == 0) { asrc2[node] = ps; adst2[node] = pd; }
    }
}

// ---------------- layer-2 aggregation: 8 nodes/block, 32 lanes/node, zero LDS ----------------
__global__ __launch_bounds__(256) void agg2(
    const float* __restrict__ xh2, const float* __restrict__ asrc2, const float* __restrict__ adst2,
    const int* __restrict__ rowptr, const int* __restrict__ csr_src,
    const float* __restrict__ b2, float* __restrict__ out, int N) {
    int tid = threadIdx.x;
    int g = tid >> 5, lane = tid & 31;
    int node = blockIdx.x * 8 + g;
    if (node >= N) return;   // no barriers below — safe
    int beg = rowptr[node];
    int deg = rowptr[node + 1] - beg;
    float adn = adst2[node];
    float acc = 0.f;
    if (deg <= DEGCAP) {
        int si0 = 0, si1 = 0;
        float e0 = -1e30f, e1 = -1e30f;
        if (lane < deg) {
            si0 = csr_src[beg + lane];
            e0 = asrc2[si0] + adn;
            e0 = fmaxf(e0, NEG * e0);
        }
        if (32 + lane < deg) {
            si1 = csr_src[beg + 32 + lane];
            e1 = asrc2[si1] + adn;
            e1 = fmaxf(e1, NEG * e1);
        }
        float m = fmaxf(e0, e1);
#pragma unroll
        for (int off = 16; off; off >>= 1) m = fmaxf(m, __shfl_xor(m, off, 32));
        float w0 = (lane < deg) ? __expf(e0 - m) : 0.f;
        float w1 = (32 + lane < deg) ? __expf(e1 - m) : 0.f;
        float dsum = w0 + w1;
#pragma unroll
        for (int off = 16; off; off >>= 1) dsum += __shfl_xor(dsum, off, 32);
        float inv = 1.f / (dsum + 1e-16f);
        int d0 = deg < 32 ? deg : 32;
        for (int i = 0; i < d0; ++i) {
            int s = __shfl(si0, i, 32);
            float a = __shfl(w0, i, 32);
            acc = fmaf(a, xh2[s * 32 + lane], acc);
        }
        for (int i = 32; i < deg; ++i) {
            int s = __shfl(si1, i - 32, 32);
            float a = __shfl(w1, i - 32, 32);
            acc = fmaf(a, xh2[s * 32 + lane], acc);
        }
        acc *= inv;
    } else {
        float m = -1e30f;
        for (int i = lane; i < deg; i += 32) {
            int s = csr_src[beg + i];
            float e = asrc2[s] + adn;
            e = fmaxf(e, NEG * e);
            m = fmaxf(m, e);
        }
#pragma unroll
        for (int off = 16; off; off >>= 1) m = fmaxf(m, __shfl_xor(m, off, 32));
        float dsum = 0.f;
        for (int i = lane; i < deg; i += 32) {
            int s = csr_src[beg + i];
            float e = asrc2[s] + adn;
            e = fmaxf(e, NEG * e);
            dsum += __expf(e - m);
        }
#pragma unroll
        for (int off = 16; off; off >>= 1) dsum += __shfl_xor(dsum, off, 32);
        float inv = 1.f / (dsum + 1e-16f);
        for (int i = 0; i < deg; ++i) {
            int s = csr_src[beg + i];
            float e = asrc2[s] + adn;
            e = fmaxf(e, NEG * e);
            acc = fmaf(__expf(e - m) * inv, xh2[s * 32 + lane], acc);
        }
    }
    out[node * 32 + lane] = acc + b2[lane];
}

extern "C" void kernel_launch(void* const* d_in, const int* in_sizes, int n_in,
                              void* d_out, int out_size, void* d_ws, size_t ws_size,
                              hipStream_t stream) {
    const float* features = (const float*)d_in[0];
    const int*   edge_idx = (const int*)d_in[1];
    const float* W1       = (const float*)d_in[2];
    const float* att_src1 = (const float*)d_in[3];
    const float* att_dst1 = (const float*)d_in[4];
    const float* b1       = (const float*)d_in[5];
    const float* W2       = (const float*)d_in[6];
    const float* att_src2 = (const float*)d_in[7];
    const float* att_dst2 = (const float*)d_in[8];
    const float* b2       = (const float*)d_in[9];
    float* out = (float*)d_out;

    const int N = in_sizes[0] / 32;          // 20000
    const int E = in_sizes[1] / 2;           // 320000
    const int Etot = E + N;
    const int nb = (N + 255) / 256;          // 79 scan blocks (<=128 assumed)
    const int* src_in = edge_idx;
    const int* dst_in = edge_idx + E;

    // workspace layout
    float* asrc1 = (float*)d_ws;             // N*8
    float* adst1 = asrc1 + (size_t)N * 8;    // N*8
    float* xh2   = adst1 + (size_t)N * 8;    // N*32
    float* asrc2 = xh2 + (size_t)N * 32;     // N
    float* adst2 = asrc2 + N;                // N
    int* rowptr  = (int*)(adst2 + N);        // N+1
    int* cursor  = rowptr + (N + 1);         // N
    int* counts  = cursor + N;               // N
    int* bsum    = counts + N;               // 128
    int* csr_src = bsum + 128;               // Etot

    // CSR build
    hipMemsetAsync(counts, 0, (size_t)N * sizeof(int), stream);
    count_edges<<<(Etot + 255) / 256, 256, 0, stream>>>(dst_in, E, N, counts);
    scan_blk<<<nb, 256, 0, stream>>>(counts, N, bsum);
    scan_add2<<<nb, 256, 0, stream>>>(counts, bsum, nb, N, rowptr, cursor);
    scatter_edges<<<(Etot + 255) / 256, 256, 0, stream>>>(src_in, dst_in, E, N, cursor, csr_src);

    // layer-1 alphas (attention fold fused in)
    alpha1<<<(N + 31) / 32, 256, 0, stream>>>(features, W1, att_src1, att_dst1, asrc1, adst1, N);

    // fused layer 1 (+ layer-2 linear + layer-2 alpha dots)
    agg1f<<<N, 256, 0, stream>>>(features, asrc1, adst1, rowptr, csr_src,
                                 W1, b1, W2, att_src2, att_dst2,
                                 xh2, asrc2, adst2, N);

    // layer 2 aggregation
    agg2<<<(N + 7) / 8, 256, 0, stream>>>(xh2, asrc2, adst2, rowptr, csr_src, b2, out, N);
}

// Round 6
// 222.423 us; speedup vs baseline: 1.1412x; 1.1412x over previous
//
#include <hip/hip_runtime.h>
#include <hip/hip_bf16.h>

#define H1 8
#define F1 256
#define NEG 0.2f
#define DEGCAP 64   // LDS path handles deg <= 64 (max deg ~45 here); fallback correct for any deg

// ---------------- CSR build ----------------
__global__ void count_edges(const int* __restrict__ dst_in, int E, int N, int* __restrict__ counts) {
    int i = blockIdx.x * blockDim.x + threadIdx.x;
    int tot = E + N;
    if (i < tot) {
        int d = (i < E) ? dst_in[i] : (i - E);   // self-loops appended
        atomicAdd(&counts[d], 1);
    }
}

// per-block exclusive scan (in-place into counts) + block sums
__global__ void scan_blk(int* __restrict__ counts, int N, int* __restrict__ bsum) {
    __shared__ int tmp[256];
    int tid = threadIdx.x;
    int i = blockIdx.x * 256 + tid;
    int v = (i < N) ? counts[i] : 0;
    tmp[tid] = v;
    __syncthreads();
    for (int off = 1; off < 256; off <<= 1) {
        int u = (tid >= off) ? tmp[tid - off] : 0;
        __syncthreads();
        tmp[tid] += u;
        __syncthreads();
    }
    if (i < N) counts[i] = tmp[tid] - v;        // exclusive within block
    if (tid == 255) bsum[blockIdx.x] = tmp[255];
}

// adds block offsets (computed per-block via LDS tree over bsum) -> rowptr/cursor; block 0 writes rowptr[N]
__global__ void scan_add2(const int* __restrict__ excl, const int* __restrict__ bsum, int nb, int N,
                          int* __restrict__ rowptr, int* __restrict__ cursor) {
    __shared__ int sb[256];
    int tid = threadIdx.x, bid = blockIdx.x;
    int v = 0;
    if (tid < nb && (bid == 0 || tid < bid)) v = bsum[tid];   // bid 0: full sum; else: prefix
    sb[tid] = v;
    __syncthreads();
    for (int off = 128; off; off >>= 1) {
        if (tid < off) sb[tid] += sb[tid + off];
        __syncthreads();
    }
    int s0 = sb[0];
    int boff = (bid == 0) ? 0 : s0;
    if (bid == 0 && tid == 0) rowptr[N] = s0;
    int i = bid * 256 + tid;
    if (i < N) {
        int rp = excl[i] + boff;
        rowptr[i] = rp;
        cursor[i] = rp;
    }
}

__global__ void scatter_edges(const int* __restrict__ src_in, const int* __restrict__ dst_in,
                              int E, int N, int* __restrict__ cursor, int* __restrict__ csr_src) {
    int i = blockIdx.x * blockDim.x + threadIdx.x;
    int tot = E + N;
    if (i < tot) {
        int s, d;
        if (i < E) { s = src_in[i]; d = dst_in[i]; }
        else       { s = i - E;     d = i - E; }
        int pos = atomicAdd(&cursor[d], 1);
        csr_src[pos] = s;
    }
}

// ---------------- layer-1 per-node attention scalars (prep_w fused in) ----------------
// block: 256 thr = 32 nodes x 8 heads
__global__ __launch_bounds__(256) void alpha1(const float* __restrict__ x, const float* __restrict__ W1,
                                              const float* __restrict__ as1, const float* __restrict__ ad1,
                                              float* __restrict__ asrc, float* __restrict__ adst, int N) {
    __shared__ float sws[8 * 33], swd[8 * 33];
    __shared__ float sx[32 * 33];
    int t = threadIdx.x;
    // fold attention vectors through W1: w1s[h][d] = sum_c W1[d, h*32+c]*as1[h,c]
    {
        int h = t >> 5, d = t & 31;
        float s1 = 0.f, d1 = 0.f;
#pragma unroll
        for (int c = 0; c < 32; ++c) {
            float w = W1[d * F1 + h * 32 + c];
            s1 = fmaf(w, as1[h * 32 + c], s1);
            d1 = fmaf(w, ad1[h * 32 + c], d1);
        }
        sws[h * 33 + d] = s1; swd[h * 33 + d] = d1;
    }
    int base = blockIdx.x * 32;
    for (int i = t; i < 1024; i += 256) {
        int r = i >> 5, d = i & 31;
        int n = base + r;
        sx[r * 33 + d] = (n < N) ? x[n * 32 + d] : 0.f;
    }
    __syncthreads();
    int r = t >> 3, h = t & 7;
    float ps = 0.f, pd = 0.f;
#pragma unroll
    for (int d = 0; d < 32; ++d) {
        float xv = sx[r * 33 + d];
        ps = fmaf(xv, sws[h * 33 + d], ps);
        pd = fmaf(xv, swd[h * 33 + d], pd);
    }
    int n = base + r;
    if (n < N) { asrc[n * 8 + h] = ps; adst[n * 8 + h] = pd; }
}

// ---------------- fused layer-1 + layer-2 linear ----------------
// block per node, 256 thr = 8 head-groups x 32 channels.
// Softmax weights cached in LDS (broadcast reads), gather 4x-unrolled for MLP.
__global__ __launch_bounds__(256) void agg1f(
    const float* __restrict__ x, const float* __restrict__ asrc, const float* __restrict__ adst,
    const int* __restrict__ rowptr, const int* __restrict__ csr_src,
    const float* __restrict__ W1, const float* __restrict__ b1,
    const float* __restrict__ W2, const float* __restrict__ as2, const float* __restrict__ ad2,
    float* __restrict__ xh2, float* __restrict__ asrc2, float* __restrict__ adst2, int N) {
    __shared__ float sA[H1][DEGCAP];   // 2 KB: per-head exp(e-m)
    __shared__ int   sS[DEGCAP];       // 256 B
    __shared__ float spart[H1][32];    // 1 KB
    int node = blockIdx.x;
    int tid = threadIdx.x, h = tid >> 5, lane = tid & 31;
    int beg = rowptr[node];
    int deg = rowptr[node + 1] - beg;
    float adn = adst[node * 8 + h];
    float acc = 0.f;

    if (deg <= DEGCAP) {
        int i0 = lane, i1 = 32 + lane;
        float e0 = -1e30f, e1 = -1e30f;
        if (i0 < deg) {
            int s = csr_src[beg + i0];
            if (h == 0) sS[i0] = s;
            e0 = asrc[s * 8 + h] + adn;
            e0 = fmaxf(e0, NEG * e0);
        }
        if (i1 < deg) {
            int s = csr_src[beg + i1];
            if (h == 0) sS[i1] = s;
            e1 = asrc[s * 8 + h] + adn;
            e1 = fmaxf(e1, NEG * e1);
        }
        float m = fmaxf(e0, e1);
#pragma unroll
        for (int off = 16; off; off >>= 1) m = fmaxf(m, __shfl_xor(m, off, 32));
        float w0 = (i0 < deg) ? __expf(e0 - m) : 0.f;
        float w1 = (i1 < deg) ? __expf(e1 - m) : 0.f;
        if (i0 < deg) sA[h][i0] = w0;
        if (i1 < deg) sA[h][i1] = w1;
        float dsum = w0 + w1;
#pragma unroll
        for (int off = 16; off; off >>= 1) dsum += __shfl_xor(dsum, off, 32);
        float inv = 1.f / (dsum + 1e-16f);
        __syncthreads();   // sS (+ own-group sA) visible
        // 4x-unrolled gather: independent accumulators, vectorized LDS reads
        float acc0 = 0.f, acc1 = 0.f, acc2 = 0.f, acc3 = 0.f;
        int i = 0;
        for (; i + 4 <= deg; i += 4) {
            int4   tt = *reinterpret_cast<const int4*>(&sS[i]);
            float4 aa = *reinterpret_cast<const float4*>(&sA[h][i]);
            acc0 = fmaf(aa.x, x[tt.x * 32 + lane], acc0);
            acc1 = fmaf(aa.y, x[tt.y * 32 + lane], acc1);
            acc2 = fmaf(aa.z, x[tt.z * 32 + lane], acc2);
            acc3 = fmaf(aa.w, x[tt.w * 32 + lane], acc3);
        }
        for (; i < deg; ++i)
            acc0 = fmaf(sA[h][i], x[sS[i] * 32 + lane], acc0);
        acc = ((acc0 + acc1) + (acc2 + acc3)) * inv;
    } else {
        // generic fallback (recompute from global) — correct for any degree
        float m = -1e30f;
        for (int i = lane; i < deg; i += 32) {
            int s = csr_src[beg + i];
            float e = asrc[s * 8 + h] + adn;
            e = fmaxf(e, NEG * e);
            m = fmaxf(m, e);
        }
#pragma unroll
        for (int off = 16; off; off >>= 1) m = fmaxf(m, __shfl_xor(m, off, 32));
        float dsum = 0.f;
        for (int i = lane; i < deg; i += 32) {
            int s = csr_src[beg + i];
            float e = asrc[s * 8 + h] + adn;
            e = fmaxf(e, NEG * e);
            dsum += __expf(e - m);
        }
#pragma unroll
        for (int off = 16; off; off >>= 1) dsum += __shfl_xor(dsum, off, 32);
        float inv = 1.f / (dsum + 1e-16f);
        for (int i = 0; i < deg; ++i) {
            int s = csr_src[beg + i];
            float e = asrc[s * 8 + h] + adn;
            e = fmaxf(e, NEG * e);
            acc = fmaf(__expf(e - m) * inv, x[s * 32 + lane], acc);
        }
    }

    // blockdiag W1 + bias + ReLU via intra-group shuffles (acc lives in lane d)
    float v = 0.f;
#pragma unroll
    for (int d = 0; d < 32; ++d) {
        float ad_ = __shfl(acc, d, 32);
        v = fmaf(ad_, W1[d * F1 + tid], v);
    }
    v += b1[tid];
    v = fmaxf(v, 0.f);

    // fused layer-2 linear: group h holds x2 cols h*32..h*32+31 in regs -> shuffles
    float p = 0.f;
#pragma unroll
    for (int k2 = 0; k2 < 32; ++k2) {
        float xv = __shfl(v, k2, 32);
        p = fmaf(xv, W2[(h * 32 + k2) * 32 + lane], p);
    }
    spart[h][lane] = p;
    __syncthreads();
    if (tid < 32) {
        float o = 0.f;
#pragma unroll
        for (int g2 = 0; g2 < 8; ++g2) o += spart[g2][tid];
        xh2[node * 32 + tid] = o;
        float ps = o * as2[tid], pd = o * ad2[tid];
#pragma unroll
        for (int off = 16; off; off >>= 1) { ps += __shfl_xor(ps, off, 32); pd += __shfl_xor(pd, off, 32); }
        if (tid == 0) { asrc2[node] = ps; adst2[node] = pd; }
    }
}

// ---------------- layer-2 aggregation: 8 nodes/block, 32 lanes/node ----------------
// Same LDS-cached softmax + unrolled gather; per-group LDS, no block barriers.
__global__ __launch_bounds__(256) void agg2(
    const float* __restrict__ xh2, const float* __restrict__ asrc2, const float* __restrict__ adst2,
    const int* __restrict__ rowptr, const int* __restrict__ csr_src,
    const float* __restrict__ b2, float* __restrict__ out, int N) {
    __shared__ float sA[8][DEGCAP];   // 2 KB
    __shared__ int   sS[8][DEGCAP];   // 2 KB
    int tid = threadIdx.x;
    int g = tid >> 5, lane = tid & 31;
    int node = blockIdx.x * 8 + g;
    if (node >= N) return;   // no barriers below — safe
    int beg = rowptr[node];
    int deg = rowptr[node + 1] - beg;
    float adn = adst2[node];
    float acc = 0.f;
    if (deg <= DEGCAP) {
        int i0 = lane, i1 = 32 + lane;
        float e0 = -1e30f, e1 = -1e30f;
        if (i0 < deg) {
            int s = csr_src[beg + i0];
            sS[g][i0] = s;
            e0 = asrc2[s] + adn;
            e0 = fmaxf(e0, NEG * e0);
        }
        if (i1 < deg) {
            int s = csr_src[beg + i1];
            sS[g][i1] = s;
            e1 = asrc2[s] + adn;
            e1 = fmaxf(e1, NEG * e1);
        }
        float m = fmaxf(e0, e1);
#pragma unroll
        for (int off = 16; off; off >>= 1) m = fmaxf(m, __shfl_xor(m, off, 32));
        float w0 = (i0 < deg) ? __expf(e0 - m) : 0.f;
        float w1 = (i1 < deg) ? __expf(e1 - m) : 0.f;
        if (i0 < deg) sA[g][i0] = w0;
        if (i1 < deg) sA[g][i1] = w1;
        float dsum = w0 + w1;
#pragma unroll
        for (int off = 16; off; off >>= 1) dsum += __shfl_xor(dsum, off, 32);
        float inv = 1.f / (dsum + 1e-16f);
        // group reads only its own writes — wave-coherent, no barrier
        float acc0 = 0.f, acc1 = 0.f, acc2 = 0.f, acc3 = 0.f;
        int i = 0;
        for (; i + 4 <= deg; i += 4) {
            int4   tt = *reinterpret_cast<const int4*>(&sS[g][i]);
            float4 aa = *reinterpret_cast<const float4*>(&sA[g][i]);
            acc0 = fmaf(aa.x, xh2[tt.x * 32 + lane], acc0);
            acc1 = fmaf(aa.y, xh2[tt.y * 32 + lane], acc1);
            acc2 = fmaf(aa.z, xh2[tt.z * 32 + lane], acc2);
            acc3 = fmaf(aa.w, xh2[tt.w * 32 + lane], acc3);
        }
        for (; i < deg; ++i)
            acc0 = fmaf(sA[g][i], xh2[sS[g][i] * 32 + lane], acc0);
        acc = ((acc0 + acc1) + (acc2 + acc3)) * inv;
    } else {
        float m = -1e30f;
        for (int i = lane; i < deg; i += 32) {
            int s = csr_src[beg + i];
            float e = asrc2[s] + adn;
            e = fmaxf(e, NEG * e);
            m = fmaxf(m, e);
        }
#pragma unroll
        for (int off = 16; off; off >>= 1) m = fmaxf(m, __shfl_xor(m, off, 32));
        float dsum = 0.f;
        for (int i = lane; i < deg; i += 32) {
            int s = csr_src[beg + i];
            float e = asrc2[s] + adn;
            e = fmaxf(e, NEG * e);
            dsum += __expf(e - m);
        }
#pragma unroll
        for (int off = 16; off; off >>= 1) dsum += __shfl_xor(dsum, off, 32);
        float inv = 1.f / (dsum + 1e-16f);
        for (int i = 0; i < deg; ++i) {
            int s = csr_src[beg + i];
            float e = asrc2[s] + adn;
            e = fmaxf(e, NEG * e);
            acc = fmaf(__expf(e - m) * inv, xh2[s * 32 + lane], acc);
        }
    }
    out[node * 32 + lane] = acc + b2[lane];
}

extern "C" void kernel_launch(void* const* d_in, const int* in_sizes, int n_in,
                              void* d_out, int out_size, void* d_ws, size_t ws_size,
                              hipStream_t stream) {
    const float* features = (const float*)d_in[0];
    const int*   edge_idx = (const int*)d_in[1];
    const float* W1       = (const float*)d_in[2];
    const float* att_src1 = (const float*)d_in[3];
    const float* att_dst1 = (const float*)d_in[4];
    const float* b1       = (const float*)d_in[5];
    const float* W2       = (const float*)d_in[6];
    const float* att_src2 = (const float*)d_in[7];
    const float* att_dst2 = (const float*)d_in[8];
    const float* b2       = (const float*)d_in[9];
    float* out = (float*)d_out;

    const int N = in_sizes[0] / 32;          // 20000
    const int E = in_sizes[1] / 2;           // 320000
    const int Etot = E + N;
    const int nb = (N + 255) / 256;          // 79 scan blocks (<=128 assumed)
    const int* src_in = edge_idx;
    const int* dst_in = edge_idx + E;

    // workspace layout
    float* asrc1 = (float*)d_ws;             // N*8
    float* adst1 = asrc1 + (size_t)N * 8;    // N*8
    float* xh2   = adst1 + (size_t)N * 8;    // N*32
    float* asrc2 = xh2 + (size_t)N * 32;     // N
    float* adst2 = asrc2 + N;                // N
    int* rowptr  = (int*)(adst2 + N);        // N+1
    int* cursor  = rowptr + (N + 1);         // N
    int* counts  = cursor + N;               // N
    int* bsum    = counts + N;               // 128
    int* csr_src = bsum + 128;               // Etot

    // CSR build
    hipMemsetAsync(counts, 0, (size_t)N * sizeof(int), stream);
    count_edges<<<(Etot + 255) / 256, 256, 0, stream>>>(dst_in, E, N, counts);
    scan_blk<<<nb, 256, 0, stream>>>(counts, N, bsum);
    scan_add2<<<nb, 256, 0, stream>>>(counts, bsum, nb, N, rowptr, cursor);
    scatter_edges<<<(Etot + 255) / 256, 256, 0, stream>>>(src_in, dst_in, E, N, cursor, csr_src);

    // layer-1 alphas (attention fold fused in)
    alpha1<<<(N + 31) / 32, 256, 0, stream>>>(features, W1, att_src1, att_dst1, asrc1, adst1, N);

    // fused layer 1 (+ layer-2 linear + layer-2 alpha dots)
    agg1f<<<N, 256, 0, stream>>>(features, asrc1, adst1, rowptr, csr_src,
                                 W1, b1, W2, att_src2, att_dst2,
                                 xh2, asrc2, adst2, N);

    // layer 2 aggregation
    agg2<<<(N + 7) / 8, 256, 0, stream>>>(xh2, asrc2, adst2, rowptr, csr_src, b2, out, N);
}

// Round 7
// 216.042 us; speedup vs baseline: 1.1749x; 1.0295x over previous
//
#include <hip/hip_runtime.h>
#include <hip/hip_bf16.h>

#define H1 8
#define F1 256
#define NEG 0.2f
#define DEGCAP 64   // fast path handles deg <= 64 (max deg ~45 here); fallback correct for any deg

// ---------------- CSR build ----------------
__global__ void count_edges(const int* __restrict__ dst_in, int E, int N, int* __restrict__ counts) {
    int i = blockIdx.x * blockDim.x + threadIdx.x;
    int tot = E + N;
    if (i < tot) {
        int d = (i < E) ? dst_in[i] : (i - E);   // self-loops appended
        atomicAdd(&counts[d], 1);
    }
}

// per-block exclusive scan (in-place into counts) + block sums
__global__ void scan_blk(int* __restrict__ counts, int N, int* __restrict__ bsum) {
    __shared__ int tmp[256];
    int tid = threadIdx.x;
    int i = blockIdx.x * 256 + tid;
    int v = (i < N) ? counts[i] : 0;
    tmp[tid] = v;
    __syncthreads();
    for (int off = 1; off < 256; off <<= 1) {
        int u = (tid >= off) ? tmp[tid - off] : 0;
        __syncthreads();
        tmp[tid] += u;
        __syncthreads();
    }
    if (i < N) counts[i] = tmp[tid] - v;        // exclusive within block
    if (tid == 255) bsum[blockIdx.x] = tmp[255];
}

// adds block offsets (computed per-block via LDS tree over bsum) -> rowptr/cursor; block 0 writes rowptr[N]
__global__ void scan_add2(const int* __restrict__ excl, const int* __restrict__ bsum, int nb, int N,
                          int* __restrict__ rowptr, int* __restrict__ cursor) {
    __shared__ int sb[256];
    int tid = threadIdx.x, bid = blockIdx.x;
    int v = 0;
    if (tid < nb && (bid == 0 || tid < bid)) v = bsum[tid];   // bid 0: full sum; else: prefix
    sb[tid] = v;
    __syncthreads();
    for (int off = 128; off; off >>= 1) {
        if (tid < off) sb[tid] += sb[tid + off];
        __syncthreads();
    }
    int s0 = sb[0];
    int boff = (bid == 0) ? 0 : s0;
    if (bid == 0 && tid == 0) rowptr[N] = s0;
    int i = bid * 256 + tid;
    if (i < N) {
        int rp = excl[i] + boff;
        rowptr[i] = rp;
        cursor[i] = rp;
    }
}

__global__ void scatter_edges(const int* __restrict__ src_in, const int* __restrict__ dst_in,
                              int E, int N, int* __restrict__ cursor, int* __restrict__ csr_src) {
    int i = blockIdx.x * blockDim.x + threadIdx.x;
    int tot = E + N;
    if (i < tot) {
        int s, d;
        if (i < E) { s = src_in[i]; d = dst_in[i]; }
        else       { s = i - E;     d = i - E; }
        int pos = atomicAdd(&cursor[d], 1);
        csr_src[pos] = s;
    }
}

// ---------------- layer-1 per-node attention scalars (prep_w fused in) ----------------
// block: 256 thr = 32 nodes x 8 heads
__global__ __launch_bounds__(256) void alpha1(const float* __restrict__ x, const float* __restrict__ W1,
                                              const float* __restrict__ as1, const float* __restrict__ ad1,
                                              float* __restrict__ asrc, float* __restrict__ adst, int N) {
    __shared__ float sws[8 * 33], swd[8 * 33];
    __shared__ float sx[32 * 33];
    int t = threadIdx.x;
    // fold attention vectors through W1: w1s[h][d] = sum_c W1[d, h*32+c]*as1[h,c]
    {
        int h = t >> 5, d = t & 31;
        float s1 = 0.f, d1 = 0.f;
#pragma unroll
        for (int c = 0; c < 32; ++c) {
            float w = W1[d * F1 + h * 32 + c];
            s1 = fmaf(w, as1[h * 32 + c], s1);
            d1 = fmaf(w, ad1[h * 32 + c], d1);
        }
        sws[h * 33 + d] = s1; swd[h * 33 + d] = d1;
    }
    int base = blockIdx.x * 32;
    for (int i = t; i < 1024; i += 256) {
        int r = i >> 5, d = i & 31;
        int n = base + r;
        sx[r * 33 + d] = (n < N) ? x[n * 32 + d] : 0.f;
    }
    __syncthreads();
    int r = t >> 3, h = t & 7;
    float ps = 0.f, pd = 0.f;
#pragma unroll
    for (int d = 0; d < 32; ++d) {
        float xv = sx[r * 33 + d];
        ps = fmaf(xv, sws[h * 33 + d], ps);
        pd = fmaf(xv, swd[h * 33 + d], pd);
    }
    int n = base + r;
    if (n < N) { asrc[n * 8 + h] = ps; adst[n * 8 + h] = pd; }
}

// ---------------- fused layer-1 + layer-2 linear ----------------
// block per node, 256 thr.
// Softmax: edge-major (thread (i=tid&63, q=tid>>6) handles edge i, heads 2q/2q+1; float2 asrc loads).
// Gather: (h=tid>>5, lane) 4x-unrolled, coalesced x rows, sA LDS broadcasts.
// Epilogue: LDS-broadcast W1/W2 (no shuffles).
__global__ __launch_bounds__(256) void agg1f(
    const float* __restrict__ x, const float* __restrict__ asrc, const float* __restrict__ adst,
    const int* __restrict__ rowptr, const int* __restrict__ csr_src,
    const float* __restrict__ W1, const float* __restrict__ b1,
    const float* __restrict__ W2, const float* __restrict__ as2, const float* __restrict__ ad2,
    float* __restrict__ xh2, float* __restrict__ asrc2, float* __restrict__ adst2, int N) {
    __shared__ float sA[H1][DEGCAP];   // 2 KB: normalized alphas
    __shared__ int   sS[DEGCAP];       // 256 B
    __shared__ float sacc[H1][33];     // 1 KB
    __shared__ float sx2[F1];          // 1 KB
    __shared__ float spart[H1][32];    // 1 KB
    int node = blockIdx.x;
    int tid = threadIdx.x, h = tid >> 5, lane = tid & 31;
    int beg = rowptr[node];
    int deg = rowptr[node + 1] - beg;
    float acc = 0.f;

    if (deg <= DEGCAP) {
        // ---- edge-major softmax: i = tid&63, heads 2q, 2q+1 (q = tid>>6) ----
        int i = tid & 63, q = tid >> 6;
        int s = (i < deg) ? csr_src[beg + i] : 0;    // coalesced per wave
        if (tid < 64 && i < deg) sS[i] = s;
        float2 adn2 = *reinterpret_cast<const float2*>(&adst[node * 8 + 2 * q]);
        float ea = -1e30f, eb = -1e30f;
        if (i < deg) {
            float2 av = *reinterpret_cast<const float2*>(&asrc[s * 8 + 2 * q]);
            ea = av.x + adn2.x; ea = fmaxf(ea, NEG * ea);
            eb = av.y + adn2.y; eb = fmaxf(eb, NEG * eb);
        }
        float ma = ea, mb = eb;
#pragma unroll
        for (int off = 32; off; off >>= 1) {
            ma = fmaxf(ma, __shfl_xor(ma, off, 64));
            mb = fmaxf(mb, __shfl_xor(mb, off, 64));
        }
        float wa = (i < deg) ? __expf(ea - ma) : 0.f;
        float wb = (i < deg) ? __expf(eb - mb) : 0.f;
        float sa = wa, sb = wb;
#pragma unroll
        for (int off = 32; off; off >>= 1) {
            sa += __shfl_xor(sa, off, 64);
            sb += __shfl_xor(sb, off, 64);
        }
        if (i < deg) {
            sA[2 * q][i]     = wa * (1.f / (sa + 1e-16f));
            sA[2 * q + 1][i] = wb * (1.f / (sb + 1e-16f));
        }
        __syncthreads();
        // ---- 4x-unrolled gather: (h, lane) layout ----
        float acc0 = 0.f, acc1 = 0.f, acc2 = 0.f, acc3 = 0.f;
        int j = 0;
        for (; j + 4 <= deg; j += 4) {
            int4   tt = *reinterpret_cast<const int4*>(&sS[j]);
            float4 aa = *reinterpret_cast<const float4*>(&sA[h][j]);
            acc0 = fmaf(aa.x, x[tt.x * 32 + lane], acc0);
            acc1 = fmaf(aa.y, x[tt.y * 32 + lane], acc1);
            acc2 = fmaf(aa.z, x[tt.z * 32 + lane], acc2);
            acc3 = fmaf(aa.w, x[tt.w * 32 + lane], acc3);
        }
        for (; j < deg; ++j)
            acc0 = fmaf(sA[h][j], x[sS[j] * 32 + lane], acc0);
        acc = (acc0 + acc1) + (acc2 + acc3);
    } else {
        // generic fallback (recompute from global) — correct for any degree
        float adn = adst[node * 8 + h];
        float m = -1e30f;
        for (int i = lane; i < deg; i += 32) {
            int s = csr_src[beg + i];
            float e = asrc[s * 8 + h] + adn;
            e = fmaxf(e, NEG * e);
            m = fmaxf(m, e);
        }
#pragma unroll
        for (int off = 16; off; off >>= 1) m = fmaxf(m, __shfl_xor(m, off, 32));
        float dsum = 0.f;
        for (int i = lane; i < deg; i += 32) {
            int s = csr_src[beg + i];
            float e = asrc[s * 8 + h] + adn;
            e = fmaxf(e, NEG * e);
            dsum += __expf(e - m);
        }
#pragma unroll
        for (int off = 16; off; off >>= 1) dsum += __shfl_xor(dsum, off, 32);
        float inv = 1.f / (dsum + 1e-16f);
        for (int i = 0; i < deg; ++i) {
            int s = csr_src[beg + i];
            float e = asrc[s * 8 + h] + adn;
            e = fmaxf(e, NEG * e);
            acc = fmaf(__expf(e - m) * inv, x[s * 32 + lane], acc);
        }
    }

    // ---- blockdiag W1 + bias + ReLU (LDS broadcast + coalesced W1) ----
    sacc[h][lane] = acc;
    __syncthreads();
    float v = 0.f;
#pragma unroll
    for (int d = 0; d < 32; ++d)
        v = fmaf(sacc[h][d], W1[d * F1 + tid], v);
    v += b1[tid];
    v = fmaxf(v, 0.f);
    sx2[tid] = v;
    __syncthreads();

    // ---- fused layer-2 linear: xh2[node, c] = sum_k x2[k] * W2[k*32+c] ----
    float p = 0.f;
#pragma unroll
    for (int k2 = 0; k2 < 32; ++k2) {
        int k = h * 32 + k2;
        p = fmaf(sx2[k], W2[k * 32 + lane], p);
    }
    spart[h][lane] = p;
    __syncthreads();
    if (tid < 32) {
        float o = 0.f;
#pragma unroll
        for (int g2 = 0; g2 < 8; ++g2) o += spart[g2][tid];
        xh2[node * 32 + tid] = o;
        float ps = o * as2[tid], pd = o * ad2[tid];
#pragma unroll
        for (int off = 16; off; off >>= 1) { ps += __shfl_xor(ps, off, 32); pd += __shfl_xor(pd, off, 32); }
        if (tid == 0) { asrc2[node] = ps; adst2[node] = pd; }
    }
}

// ---------------- layer-2 aggregation: 8 nodes/block, 32 lanes/node ----------------
// LDS-cached softmax + unrolled gather; per-group LDS, no block barriers.
__global__ __launch_bounds__(256) void agg2(
    const float* __restrict__ xh2, const float* __restrict__ asrc2, const float* __restrict__ adst2,
    const int* __restrict__ rowptr, const int* __restrict__ csr_src,
    const float* __restrict__ b2, float* __restrict__ out, int N) {
    __shared__ float sA[8][DEGCAP];   // 2 KB
    __shared__ int   sS[8][DEGCAP];   // 2 KB
    int tid = threadIdx.x;
    int g = tid >> 5, lane = tid & 31;
    int node = blockIdx.x * 8 + g;
    if (node >= N) return;   // no barriers below — safe
    int beg = rowptr[node];
    int deg = rowptr[node + 1] - beg;
    float adn = adst2[node];
    float acc = 0.f;
    if (deg <= DEGCAP) {
        int i0 = lane, i1 = 32 + lane;
        float e0 = -1e30f, e1 = -1e30f;
        if (i0 < deg) {
            int s = csr_src[beg + i0];
            sS[g][i0] = s;
            e0 = asrc2[s] + adn;
            e0 = fmaxf(e0, NEG * e0);
        }
        if (i1 < deg) {
            int s = csr_src[beg + i1];
            sS[g][i1] = s;
            e1 = asrc2[s] + adn;
            e1 = fmaxf(e1, NEG * e1);
        }
        float m = fmaxf(e0, e1);
#pragma unroll
        for (int off = 16; off; off >>= 1) m = fmaxf(m, __shfl_xor(m, off, 32));
        float w0 = (i0 < deg) ? __expf(e0 - m) : 0.f;
        float w1 = (i1 < deg) ? __expf(e1 - m) : 0.f;
        if (i0 < deg) sA[g][i0] = w0;
        if (i1 < deg) sA[g][i1] = w1;
        float dsum = w0 + w1;
#pragma unroll
        for (int off = 16; off; off >>= 1) dsum += __shfl_xor(dsum, off, 32);
        float inv = 1.f / (dsum + 1e-16f);
        // group reads only its own writes — wave-coherent, no barrier
        float acc0 = 0.f, acc1 = 0.f, acc2 = 0.f, acc3 = 0.f;
        int i = 0;
        for (; i + 4 <= deg; i += 4) {
            int4   tt = *reinterpret_cast<const int4*>(&sS[g][i]);
            float4 aa = *reinterpret_cast<const float4*>(&sA[g][i]);
            acc0 = fmaf(aa.x, xh2[tt.x * 32 + lane], acc0);
            acc1 = fmaf(aa.y, xh2[tt.y * 32 + lane], acc1);
            acc2 = fmaf(aa.z, xh2[tt.z * 32 + lane], acc2);
            acc3 = fmaf(aa.w, xh2[tt.w * 32 + lane], acc3);
        }
        for (; i < deg; ++i)
            acc0 = fmaf(sA[g][i], xh2[sS[g][i] * 32 + lane], acc0);
        acc = ((acc0 + acc1) + (acc2 + acc3)) * inv;
    } else {
        float m = -1e30f;
        for (int i = lane; i < deg; i += 32) {
            int s = csr_src[beg + i];
            float e = asrc2[s] + adn;
            e = fmaxf(e, NEG * e);
            m = fmaxf(m, e);
        }
#pragma unroll
        for (int off = 16; off; off >>= 1) m = fmaxf(m, __shfl_xor(m, off, 32));
        float dsum = 0.f;
        for (int i = lane; i < deg; i += 32) {
            int s = csr_src[beg + i];
            float e = asrc2[s] + adn;
            e = fmaxf(e, NEG * e);
            dsum += __expf(e - m);
        }
#pragma unroll
        for (int off = 16; off; off >>= 1) dsum += __shfl_xor(dsum, off, 32);
        float inv = 1.f / (dsum + 1e-16f);
        for (int i = 0; i < deg; ++i) {
            int s = csr_src[beg + i];
            float e = asrc2[s] + adn;
            e = fmaxf(e, NEG * e);
            acc = fmaf(__expf(e - m) * inv, xh2[s * 32 + lane], acc);
        }
    }
    out[node * 32 + lane] = acc + b2[lane];
}

extern "C" void kernel_launch(void* const* d_in, const int* in_sizes, int n_in,
                              void* d_out, int out_size, void* d_ws, size_t ws_size,
                              hipStream_t stream) {
    const float* features = (const float*)d_in[0];
    const int*   edge_idx = (const int*)d_in[1];
    const float* W1       = (const float*)d_in[2];
    const float* att_src1 = (const float*)d_in[3];
    const float* att_dst1 = (const float*)d_in[4];
    const float* b1       = (const float*)d_in[5];
    const float* W2       = (const float*)d_in[6];
    const float* att_src2 = (const float*)d_in[7];
    const float* att_dst2 = (const float*)d_in[8];
    const float* b2       = (const float*)d_in[9];
    float* out = (float*)d_out;

    const int N = in_sizes[0] / 32;          // 20000
    const int E = in_sizes[1] / 2;           // 320000
    const int Etot = E + N;
    const int nb = (N + 255) / 256;          // 79 scan blocks (<=128 assumed)
    const int* src_in = edge_idx;
    const int* dst_in = edge_idx + E;

    // workspace layout
    float* asrc1 = (float*)d_ws;             // N*8
    float* adst1 = asrc1 + (size_t)N * 8;    // N*8
    float* xh2   = adst1 + (size_t)N * 8;    // N*32
    float* asrc2 = xh2 + (size_t)N * 32;     // N
    float* adst2 = asrc2 + N;                // N
    int* rowptr  = (int*)(adst2 + N);        // N+1
    int* cursor  = rowptr + (N + 1);         // N
    int* counts  = cursor + N;               // N
    int* bsum    = counts + N;               // 128
    int* csr_src = bsum + 128;               // Etot

    // CSR build
    hipMemsetAsync(counts, 0, (size_t)N * sizeof(int), stream);
    count_edges<<<(Etot + 255) / 256, 256, 0, stream>>>(dst_in, E, N, counts);
    scan_blk<<<nb, 256, 0, stream>>>(counts, N, bsum);
    scan_add2<<<nb, 256, 0, stream>>>(counts, bsum, nb, N, rowptr, cursor);
    scatter_edges<<<(Etot + 255) / 256, 256, 0, stream>>>(src_in, dst_in, E, N, cursor, csr_src);

    // layer-1 alphas (attention fold fused in)
    alpha1<<<(N + 31) / 32, 256, 0, stream>>>(features, W1, att_src1, att_dst1, asrc1, adst1, N);

    // fused layer 1 (+ layer-2 linear + layer-2 alpha dots)
    agg1f<<<N, 256, 0, stream>>>(features, asrc1, adst1, rowptr, csr_src,
                                 W1, b1, W2, att_src2, att_dst2,
                                 xh2, asrc2, adst2, N);

    // layer 2 aggregation
    agg2<<<(N + 7) / 8, 256, 0, stream>>>(xh2, asrc2, adst2, rowptr, csr_src, b2, out, N);
}

// Round 8
// 202.243 us; speedup vs baseline: 1.2550x; 1.0682x over previous
//
#include <hip/hip_runtime.h>
#include <hip/hip_bf16.h>

#define H1 8
#define F1 256
#define NEG 0.2f
#define DEGCAP 64   // fast path handles deg <= 64 (max deg ~45 here); fallback correct for any deg
#define NPB 16      // nodes per block in mlp kernel

// ---------------- CSR build ----------------
__global__ void count_edges(const int* __restrict__ dst_in, int E, int N, int* __restrict__ counts) {
    int i = blockIdx.x * blockDim.x + threadIdx.x;
    int tot = E + N;
    if (i < tot) {
        int d = (i < E) ? dst_in[i] : (i - E);   // self-loops appended
        atomicAdd(&counts[d], 1);
    }
}

// per-block exclusive scan (in-place into counts) + block sums
__global__ void scan_blk(int* __restrict__ counts, int N, int* __restrict__ bsum) {
    __shared__ int tmp[256];
    int tid = threadIdx.x;
    int i = blockIdx.x * 256 + tid;
    int v = (i < N) ? counts[i] : 0;
    tmp[tid] = v;
    __syncthreads();
    for (int off = 1; off < 256; off <<= 1) {
        int u = (tid >= off) ? tmp[tid - off] : 0;
        __syncthreads();
        tmp[tid] += u;
        __syncthreads();
    }
    if (i < N) counts[i] = tmp[tid] - v;        // exclusive within block
    if (tid == 255) bsum[blockIdx.x] = tmp[255];
}

// adds block offsets (computed per-block via LDS tree over bsum) -> rowptr/cursor; block 0 writes rowptr[N]
__global__ void scan_add2(const int* __restrict__ excl, const int* __restrict__ bsum, int nb, int N,
                          int* __restrict__ rowptr, int* __restrict__ cursor) {
    __shared__ int sb[256];
    int tid = threadIdx.x, bid = blockIdx.x;
    int v = 0;
    if (tid < nb && (bid == 0 || tid < bid)) v = bsum[tid];   // bid 0: full sum; else: prefix
    sb[tid] = v;
    __syncthreads();
    for (int off = 128; off; off >>= 1) {
        if (tid < off) sb[tid] += sb[tid + off];
        __syncthreads();
    }
    int s0 = sb[0];
    int boff = (bid == 0) ? 0 : s0;
    if (bid == 0 && tid == 0) rowptr[N] = s0;
    int i = bid * 256 + tid;
    if (i < N) {
        int rp = excl[i] + boff;
        rowptr[i] = rp;
        cursor[i] = rp;
    }
}

__global__ void scatter_edges(const int* __restrict__ src_in, const int* __restrict__ dst_in,
                              int E, int N, int* __restrict__ cursor, int* __restrict__ csr_src) {
    int i = blockIdx.x * blockDim.x + threadIdx.x;
    int tot = E + N;
    if (i < tot) {
        int s, d;
        if (i < E) { s = src_in[i]; d = dst_in[i]; }
        else       { s = i - E;     d = i - E; }
        int pos = atomicAdd(&cursor[d], 1);
        csr_src[pos] = s;
    }
}

// ---------------- layer-1 per-node attention scalars (prep_w fused in) ----------------
// block: 256 thr = 32 nodes x 8 heads
__global__ __launch_bounds__(256) void alpha1(const float* __restrict__ x, const float* __restrict__ W1,
                                              const float* __restrict__ as1, const float* __restrict__ ad1,
                                              float* __restrict__ asrc, float* __restrict__ adst, int N) {
    __shared__ float sws[8 * 33], swd[8 * 33];
    __shared__ float sx[32 * 33];
    int t = threadIdx.x;
    // fold attention vectors through W1: w1s[h][d] = sum_c W1[d, h*32+c]*as1[h,c]
    {
        int h = t >> 5, d = t & 31;
        float s1 = 0.f, d1 = 0.f;
#pragma unroll
        for (int c = 0; c < 32; ++c) {
            float w = W1[d * F1 + h * 32 + c];
            s1 = fmaf(w, as1[h * 32 + c], s1);
            d1 = fmaf(w, ad1[h * 32 + c], d1);
        }
        sws[h * 33 + d] = s1; swd[h * 33 + d] = d1;
    }
    int base = blockIdx.x * 32;
    for (int i = t; i < 1024; i += 256) {
        int r = i >> 5, d = i & 31;
        int n = base + r;
        sx[r * 33 + d] = (n < N) ? x[n * 32 + d] : 0.f;
    }
    __syncthreads();
    int r = t >> 3, h = t & 7;
    float ps = 0.f, pd = 0.f;
#pragma unroll
    for (int d = 0; d < 32; ++d) {
        float xv = sx[r * 33 + d];
        ps = fmaf(xv, sws[h * 33 + d], ps);
        pd = fmaf(xv, swd[h * 33 + d], pd);
    }
    int n = base + r;
    if (n < N) { asrc[n * 8 + h] = ps; adst[n * 8 + h] = pd; }
}

// ---------------- layer-1 aggregation in input space (light) ----------------
// block per node, 256 thr. Edge-major softmax + 4x-unrolled gather (R7-validated).
// Writes AGG[node, h*32+c] = sum_e alpha[h,e] * x[src_e, c]  — MLP applied in a separate kernel.
__global__ __launch_bounds__(256) void agg1(
    const float* __restrict__ x, const float* __restrict__ asrc, const float* __restrict__ adst,
    const int* __restrict__ rowptr, const int* __restrict__ csr_src,
    float* __restrict__ AGG, int N) {
    __shared__ float sA[H1][DEGCAP];   // 2 KB: normalized alphas
    __shared__ int   sS[DEGCAP];       // 256 B
    int node = blockIdx.x;
    int tid = threadIdx.x, h = tid >> 5, lane = tid & 31;
    int beg = rowptr[node];
    int deg = rowptr[node + 1] - beg;
    float acc = 0.f;

    if (deg <= DEGCAP) {
        // ---- edge-major softmax: i = tid&63, heads 2q, 2q+1 (q = tid>>6) ----
        int i = tid & 63, q = tid >> 6;
        int s = (i < deg) ? csr_src[beg + i] : 0;    // coalesced per wave
        if (tid < 64 && i < deg) sS[i] = s;
        float2 adn2 = *reinterpret_cast<const float2*>(&adst[node * 8 + 2 * q]);
        float ea = -1e30f, eb = -1e30f;
        if (i < deg) {
            float2 av = *reinterpret_cast<const float2*>(&asrc[s * 8 + 2 * q]);
            ea = av.x + adn2.x; ea = fmaxf(ea, NEG * ea);
            eb = av.y + adn2.y; eb = fmaxf(eb, NEG * eb);
        }
        float ma = ea, mb = eb;
#pragma unroll
        for (int off = 32; off; off >>= 1) {
            ma = fmaxf(ma, __shfl_xor(ma, off, 64));
            mb = fmaxf(mb, __shfl_xor(mb, off, 64));
        }
        float wa = (i < deg) ? __expf(ea - ma) : 0.f;
        float wb = (i < deg) ? __expf(eb - mb) : 0.f;
        float sa = wa, sb = wb;
#pragma unroll
        for (int off = 32; off; off >>= 1) {
            sa += __shfl_xor(sa, off, 64);
            sb += __shfl_xor(sb, off, 64);
        }
        if (i < deg) {
            sA[2 * q][i]     = wa * (1.f / (sa + 1e-16f));
            sA[2 * q + 1][i] = wb * (1.f / (sb + 1e-16f));
        }
        __syncthreads();
        // ---- 4x-unrolled gather: (h, lane) layout ----
        float acc0 = 0.f, acc1 = 0.f, acc2 = 0.f, acc3 = 0.f;
        int j = 0;
        for (; j + 4 <= deg; j += 4) {
            int4   tt = *reinterpret_cast<const int4*>(&sS[j]);
            float4 aa = *reinterpret_cast<const float4*>(&sA[h][j]);
            acc0 = fmaf(aa.x, x[tt.x * 32 + lane], acc0);
            acc1 = fmaf(aa.y, x[tt.y * 32 + lane], acc1);
            acc2 = fmaf(aa.z, x[tt.z * 32 + lane], acc2);
            acc3 = fmaf(aa.w, x[tt.w * 32 + lane], acc3);
        }
        for (; j < deg; ++j)
            acc0 = fmaf(sA[h][j], x[sS[j] * 32 + lane], acc0);
        acc = (acc0 + acc1) + (acc2 + acc3);
    } else {
        // generic fallback (recompute from global) — correct for any degree
        float adn = adst[node * 8 + h];
        float m = -1e30f;
        for (int i = lane; i < deg; i += 32) {
            int s = csr_src[beg + i];
            float e = asrc[s * 8 + h] + adn;
            e = fmaxf(e, NEG * e);
            m = fmaxf(m, e);
        }
#pragma unroll
        for (int off = 16; off; off >>= 1) m = fmaxf(m, __shfl_xor(m, off, 32));
        float dsum = 0.f;
        for (int i = lane; i < deg; i += 32) {
            int s = csr_src[beg + i];
            float e = asrc[s * 8 + h] + adn;
            e = fmaxf(e, NEG * e);
            dsum += __expf(e - m);
        }
#pragma unroll
        for (int off = 16; off; off >>= 1) dsum += __shfl_xor(dsum, off, 32);
        float inv = 1.f / (dsum + 1e-16f);
        for (int i = 0; i < deg; ++i) {
            int s = csr_src[beg + i];
            float e = asrc[s * 8 + h] + adn;
            e = fmaxf(e, NEG * e);
            acc = fmaf(__expf(e - m) * inv, x[s * 32 + lane], acc);
        }
    }
    AGG[(size_t)node * F1 + tid] = acc;   // coalesced 1KB write
}

// ---------------- batched MLP: x2 = relu(AGG @ blockdiag(W1) + b1); xh2 = x2 @ W2; alpha2 dots ----------------
// 16 nodes per block, 256 thr. Weights register-resident, AGG/x2 tiles in LDS.
__global__ __launch_bounds__(256) void mlp(
    const float* __restrict__ AGG, const float* __restrict__ W1, const float* __restrict__ b1,
    const float* __restrict__ W2, const float* __restrict__ as2, const float* __restrict__ ad2,
    float* __restrict__ xh2, float* __restrict__ asrc2, float* __restrict__ adst2, int N) {
    __shared__ float sT[NPB][F1];        // 16 KB: AGG tile, then reused as x2 tile
    __shared__ float spart[NPB][8][32];  // 16 KB
    int tid = threadIdx.x;
    int h = tid >> 5, c = tid & 31;      // h = head (phase 1) = k-group (phase 2)
    int base = blockIdx.x * NPB;

    // stage AGG tile (float4 coalesced)
    for (int i = tid; i < NPB * (F1 / 4); i += 256) {
        int n = i >> 6, j = i & 63;
        float4 v = (base + n < N) ? reinterpret_cast<const float4*>(AGG)[(size_t)(base + n) * 64 + j]
                                  : make_float4(0.f, 0.f, 0.f, 0.f);
        reinterpret_cast<float4*>(&sT[n][0])[j] = v;
    }
    // W1 column for output col tid -> registers
    float w1r[32];
#pragma unroll
    for (int d = 0; d < 32; ++d) w1r[d] = W1[d * F1 + tid];
    float bb = b1[tid];
    __syncthreads();

    // phase 1: x2[n, tid] for 16 nodes (LDS broadcast reads within head-group)
    float x2r[NPB];
#pragma unroll
    for (int n = 0; n < NPB; ++n) {
        float v = 0.f;
#pragma unroll
        for (int j = 0; j < 8; ++j) {
            float4 a4 = *reinterpret_cast<const float4*>(&sT[n][h * 32 + 4 * j]);
            v = fmaf(a4.x, w1r[4 * j],     v);
            v = fmaf(a4.y, w1r[4 * j + 1], v);
            v = fmaf(a4.z, w1r[4 * j + 2], v);
            v = fmaf(a4.w, w1r[4 * j + 3], v);
        }
        x2r[n] = fmaxf(v + bb, 0.f);
    }
    __syncthreads();   // done reading AGG tile
#pragma unroll
    for (int n = 0; n < NPB; ++n) sT[n][tid] = x2r[n];
    // W2 rows h*32..h*32+31, col c -> registers
    float w2r[32];
#pragma unroll
    for (int k2 = 0; k2 < 32; ++k2) w2r[k2] = W2[(h * 32 + k2) * 32 + c];
    __syncthreads();

    // phase 2: partial dot over k-group h
#pragma unroll
    for (int n = 0; n < NPB; ++n) {
        float p = 0.f;
#pragma unroll
        for (int j = 0; j < 8; ++j) {
            float4 a4 = *reinterpret_cast<const float4*>(&sT[n][h * 32 + 4 * j]);
            p = fmaf(a4.x, w2r[4 * j],     p);
            p = fmaf(a4.y, w2r[4 * j + 1], p);
            p = fmaf(a4.z, w2r[4 * j + 2], p);
            p = fmaf(a4.w, w2r[4 * j + 3], p);
        }
        spart[n][h][c] = p;
    }
    __syncthreads();

    // reduce 8 partials -> xh2, plus alpha2 dots
#pragma unroll
    for (int rep = 0; rep < 2; ++rep) {
        int n = (tid >> 5) + 8 * rep;
        float o = 0.f;
#pragma unroll
        for (int q = 0; q < 8; ++q) o += spart[n][q][c];
        int node = base + n;
        float ps = o * as2[c], pd = o * ad2[c];
#pragma unroll
        for (int off = 16; off; off >>= 1) { ps += __shfl_xor(ps, off, 32); pd += __shfl_xor(pd, off, 32); }
        if (node < N) {
            xh2[(size_t)node * 32 + c] = o;
            if (c == 0) { asrc2[node] = ps; adst2[node] = pd; }
        }
    }
}

// ---------------- layer-2 aggregation: 8 nodes/block, 32 lanes/node ----------------
// LDS-cached softmax + unrolled gather; per-group LDS, no block barriers.
__global__ __launch_bounds__(256) void agg2(
    const float* __restrict__ xh2, const float* __restrict__ asrc2, const float* __restrict__ adst2,
    const int* __restrict__ rowptr, const int* __restrict__ csr_src,
    const float* __restrict__ b2, float* __restrict__ out, int N) {
    __shared__ float sA[8][DEGCAP];   // 2 KB
    __shared__ int   sS[8][DEGCAP];   // 2 KB
    int tid = threadIdx.x;
    int g = tid >> 5, lane = tid & 31;
    int node = blockIdx.x * 8 + g;
    if (node >= N) return;   // no barriers below — safe
    int beg = rowptr[node];
    int deg = rowptr[node + 1] - beg;
    float adn = adst2[node];
    float acc = 0.f;
    if (deg <= DEGCAP) {
        int i0 = lane, i1 = 32 + lane;
        float e0 = -1e30f, e1 = -1e30f;
        if (i0 < deg) {
            int s = csr_src[beg + i0];
            sS[g][i0] = s;
            e0 = asrc2[s] + adn;
            e0 = fmaxf(e0, NEG * e0);
        }
        if (i1 < deg) {
            int s = csr_src[beg + i1];
            sS[g][i1] = s;
            e1 = asrc2[s] + adn;
            e1 = fmaxf(e1, NEG * e1);
        }
        float m = fmaxf(e0, e1);
#pragma unroll
        for (int off = 16; off; off >>= 1) m = fmaxf(m, __shfl_xor(m, off, 32));
        float w0 = (i0 < deg) ? __expf(e0 - m) : 0.f;
        float w1 = (i1 < deg) ? __expf(e1 - m) : 0.f;
        if (i0 < deg) sA[g][i0] = w0;
        if (i1 < deg) sA[g][i1] = w1;
        float dsum = w0 + w1;
#pragma unroll
        for (int off = 16; off; off >>= 1) dsum += __shfl_xor(dsum, off, 32);
        float inv = 1.f / (dsum + 1e-16f);
        // group reads only its own writes — wave-coherent, no barrier
        float acc0 = 0.f, acc1 = 0.f, acc2 = 0.f, acc3 = 0.f;
        int i = 0;
        for (; i + 4 <= deg; i += 4) {
            int4   tt = *reinterpret_cast<const int4*>(&sS[g][i]);
            float4 aa = *reinterpret_cast<const float4*>(&sA[g][i]);
            acc0 = fmaf(aa.x, xh2[tt.x * 32 + lane], acc0);
            acc1 = fmaf(aa.y, xh2[tt.y * 32 + lane], acc1);
            acc2 = fmaf(aa.z, xh2[tt.z * 32 + lane], acc2);
            acc3 = fmaf(aa.w, xh2[tt.w * 32 + lane], acc3);
        }
        for (; i < deg; ++i)
            acc0 = fmaf(sA[g][i], xh2[sS[g][i] * 32 + lane], acc0);
        acc = ((acc0 + acc1) + (acc2 + acc3)) * inv;
    } else {
        float m = -1e30f;
        for (int i = lane; i < deg; i += 32) {
            int s = csr_src[beg + i];
            float e = asrc2[s] + adn;
            e = fmaxf(e, NEG * e);
            m = fmaxf(m, e);
        }
#pragma unroll
        for (int off = 16; off; off >>= 1) m = fmaxf(m, __shfl_xor(m, off, 32));
        float dsum = 0.f;
        for (int i = lane; i < deg; i += 32) {
            int s = csr_src[beg + i];
            float e = asrc2[s] + adn;
            e = fmaxf(e, NEG * e);
            dsum += __expf(e - m);
        }
#pragma unroll
        for (int off = 16; off; off >>= 1) dsum += __shfl_xor(dsum, off, 32);
        float inv = 1.f / (dsum + 1e-16f);
        for (int i = 0; i < deg; ++i) {
            int s = csr_src[beg + i];
            float e = asrc2[s] + adn;
            e = fmaxf(e, NEG * e);
            acc = fmaf(__expf(e - m) * inv, xh2[s * 32 + lane], acc);
        }
    }
    out[node * 32 + lane] = acc + b2[lane];
}

extern "C" void kernel_launch(void* const* d_in, const int* in_sizes, int n_in,
                              void* d_out, int out_size, void* d_ws, size_t ws_size,
                              hipStream_t stream) {
    const float* features = (const float*)d_in[0];
    const int*   edge_idx = (const int*)d_in[1];
    const float* W1       = (const float*)d_in[2];
    const float* att_src1 = (const float*)d_in[3];
    const float* att_dst1 = (const float*)d_in[4];
    const float* b1       = (const float*)d_in[5];
    const float* W2       = (const float*)d_in[6];
    const float* att_src2 = (const float*)d_in[7];
    const float* att_dst2 = (const float*)d_in[8];
    const float* b2       = (const float*)d_in[9];
    float* out = (float*)d_out;

    const int N = in_sizes[0] / 32;          // 20000
    const int E = in_sizes[1] / 2;           // 320000
    const int Etot = E + N;
    const int nb = (N + 255) / 256;          // 79 scan blocks (<=128 assumed)
    const int* src_in = edge_idx;
    const int* dst_in = edge_idx + E;

    // workspace layout
    float* AGG   = (float*)d_ws;             // N*256 (20 MB)
    float* asrc1 = AGG + (size_t)N * F1;     // N*8
    float* adst1 = asrc1 + (size_t)N * 8;    // N*8
    float* xh2   = adst1 + (size_t)N * 8;    // N*32
    float* asrc2 = xh2 + (size_t)N * 32;     // N
    float* adst2 = asrc2 + N;                // N
    int* rowptr  = (int*)(adst2 + N);        // N+1
    int* cursor  = rowptr + (N + 1);         // N
    int* counts  = cursor + N;               // N
    int* bsum    = counts + N;               // 128
    int* csr_src = bsum + 128;               // Etot

    // CSR build
    hipMemsetAsync(counts, 0, (size_t)N * sizeof(int), stream);
    count_edges<<<(Etot + 255) / 256, 256, 0, stream>>>(dst_in, E, N, counts);
    scan_blk<<<nb, 256, 0, stream>>>(counts, N, bsum);
    scan_add2<<<nb, 256, 0, stream>>>(counts, bsum, nb, N, rowptr, cursor);
    scatter_edges<<<(Etot + 255) / 256, 256, 0, stream>>>(src_in, dst_in, E, N, cursor, csr_src);

    // layer-1 alphas (attention fold fused in)
    alpha1<<<(N + 31) / 32, 256, 0, stream>>>(features, W1, att_src1, att_dst1, asrc1, adst1, N);

    // layer-1 aggregation (input space)
    agg1<<<N, 256, 0, stream>>>(features, asrc1, adst1, rowptr, csr_src, AGG, N);

    // batched MLP (W1 + ReLU + W2) + layer-2 alpha dots
    mlp<<<(N + NPB - 1) / NPB, 256, 0, stream>>>(AGG, W1, b1, W2, att_src2, att_dst2,
                                                 xh2, asrc2, adst2, N);

    // layer 2 aggregation
    agg2<<<(N + 7) / 8, 256, 0, stream>>>(xh2, asrc2, adst2, rowptr, csr_src, b2, out, N);
}

// Round 9
// 192.956 us; speedup vs baseline: 1.3154x; 1.0481x over previous
//
#include <hip/hip_runtime.h>
#include <hip/hip_bf16.h>

#define H1 8
#define F1 256
#define NEG 0.2f
#define DEGCAP 64   // fast path handles deg <= 64 (max deg ~45 here); fallback correct for any deg
#define NPB 16      // nodes per block in mlp kernel

// ---------------- CSR build ----------------
// per-block exclusive scan (in-place into counts) + block sums
__global__ void scan_blk(int* __restrict__ counts, int N, int* __restrict__ bsum) {
    __shared__ int tmp[256];
    int tid = threadIdx.x;
    int i = blockIdx.x * 256 + tid;
    int v = (i < N) ? counts[i] : 0;
    tmp[tid] = v;
    __syncthreads();
    for (int off = 1; off < 256; off <<= 1) {
        int u = (tid >= off) ? tmp[tid - off] : 0;
        __syncthreads();
        tmp[tid] += u;
        __syncthreads();
    }
    if (i < N) counts[i] = tmp[tid] - v;        // exclusive within block
    if (tid == 255) bsum[blockIdx.x] = tmp[255];
}

// adds block offsets (computed per-block via LDS tree over bsum) -> rowptr/cursor; block 0 writes rowptr[N]
__global__ void scan_add2(const int* __restrict__ excl, const int* __restrict__ bsum, int nb, int N,
                          int* __restrict__ rowptr, int* __restrict__ cursor) {
    __shared__ int sb[256];
    int tid = threadIdx.x, bid = blockIdx.x;
    int v = 0;
    if (tid < nb && (bid == 0 || tid < bid)) v = bsum[tid];   // bid 0: full sum; else: prefix
    sb[tid] = v;
    __syncthreads();
    for (int off = 128; off; off >>= 1) {
        if (tid < off) sb[tid] += sb[tid + off];
        __syncthreads();
    }
    int s0 = sb[0];
    int boff = (bid == 0) ? 0 : s0;
    if (bid == 0 && tid == 0) rowptr[N] = s0;
    int i = bid * 256 + tid;
    if (i < N) {
        int rp = excl[i] + boff;
        rowptr[i] = rp;
        cursor[i] = rp;
    }
}

__global__ void scatter_edges(const int* __restrict__ src_in, const int* __restrict__ dst_in,
                              int E, int N, int* __restrict__ cursor, int* __restrict__ csr_src) {
    int i = blockIdx.x * blockDim.x + threadIdx.x;
    int tot = E + N;
    if (i < tot) {
        int s, d;
        if (i < E) { s = src_in[i]; d = dst_in[i]; }
        else       { s = i - E;     d = i - E; }
        int pos = atomicAdd(&cursor[d], 1);
        csr_src[pos] = s;
    }
}

// ---------------- fused: edge counting (blocks < CB)  ||  layer-1 alpha scalars (blocks >= CB) ----------------
// alpha part: 256 thr = 32 nodes x 8 heads, prep_w fold fused in.
__global__ __launch_bounds__(256) void count_alpha(
    const int* __restrict__ dst_in, int E, int N, int* __restrict__ counts, int CB,
    const float* __restrict__ x, const float* __restrict__ W1,
    const float* __restrict__ as1, const float* __restrict__ ad1,
    float* __restrict__ asrc, float* __restrict__ adst) {
    __shared__ float sws[8 * 33], swd[8 * 33];
    __shared__ float sx[32 * 33];
    if (blockIdx.x < CB) {
        int tot = E + N;
        for (int i = blockIdx.x * 256 + threadIdx.x; i < tot; i += CB * 256) {
            int d = (i < E) ? dst_in[i] : (i - E);   // self-loops appended
            atomicAdd(&counts[d], 1);
        }
        return;
    }
    int t = threadIdx.x;
    {
        int h = t >> 5, d = t & 31;
        float s1 = 0.f, d1 = 0.f;
#pragma unroll
        for (int c = 0; c < 32; ++c) {
            float w = W1[d * F1 + h * 32 + c];
            s1 = fmaf(w, as1[h * 32 + c], s1);
            d1 = fmaf(w, ad1[h * 32 + c], d1);
        }
        sws[h * 33 + d] = s1; swd[h * 33 + d] = d1;
    }
    int base = (blockIdx.x - CB) * 32;
    for (int i = t; i < 1024; i += 256) {
        int r = i >> 5, d = i & 31;
        int n = base + r;
        sx[r * 33 + d] = (n < N) ? x[n * 32 + d] : 0.f;
    }
    __syncthreads();
    int r = t >> 3, h = t & 7;
    float ps = 0.f, pd = 0.f;
#pragma unroll
    for (int d = 0; d < 32; ++d) {
        float xv = sx[r * 33 + d];
        ps = fmaf(xv, sws[h * 33 + d], ps);
        pd = fmaf(xv, swd[h * 33 + d], pd);
    }
    int n = base + r;
    if (n < N) { asrc[n * 8 + h] = ps; adst[n * 8 + h] = pd; }
}

// ---------------- layer-1 aggregation in input space ----------------
// block per node, 256 thr. Edge-major softmax; zero-padded alphas -> full 8-wide gather batches, no tail.
__global__ __launch_bounds__(256) void agg1(
    const float* __restrict__ x, const float* __restrict__ asrc, const float* __restrict__ adst,
    const int* __restrict__ rowptr, const int* __restrict__ csr_src,
    float* __restrict__ AGG, int N) {
    __shared__ float sA[H1][DEGCAP];   // 2 KB: normalized alphas (zero-padded)
    __shared__ int   sS[DEGCAP];       // 256 B (zero-padded)
    int node = blockIdx.x;
    int tid = threadIdx.x, h = tid >> 5, lane = tid & 31;
    int beg = rowptr[node];
    int deg = rowptr[node + 1] - beg;
    float acc = 0.f;

    if (deg <= DEGCAP) {
        // ---- edge-major softmax: i = tid&63, heads 2q, 2q+1 (q = tid>>6) ----
        int i = tid & 63, q = tid >> 6;
        int s = (i < deg) ? csr_src[beg + i] : 0;    // coalesced per wave; 0 pad
        if (tid < 64) sS[i] = s;                     // all 64 slots written
        float2 adn2 = *reinterpret_cast<const float2*>(&adst[node * 8 + 2 * q]);
        float ea = -1e30f, eb = -1e30f;
        if (i < deg) {
            float2 av = *reinterpret_cast<const float2*>(&asrc[s * 8 + 2 * q]);
            ea = av.x + adn2.x; ea = fmaxf(ea, NEG * ea);
            eb = av.y + adn2.y; eb = fmaxf(eb, NEG * eb);
        }
        float ma = ea, mb = eb;
#pragma unroll
        for (int off = 32; off; off >>= 1) {
            ma = fmaxf(ma, __shfl_xor(ma, off, 64));
            mb = fmaxf(mb, __shfl_xor(mb, off, 64));
        }
        float wa = (i < deg) ? __expf(ea - ma) : 0.f;
        float wb = (i < deg) ? __expf(eb - mb) : 0.f;
        float sa = wa, sb = wb;
#pragma unroll
        for (int off = 32; off; off >>= 1) {
            sa += __shfl_xor(sa, off, 64);
            sb += __shfl_xor(sb, off, 64);
        }
        sA[2 * q][i]     = wa * (1.f / (sa + 1e-16f));   // unconditional: 0 beyond deg
        sA[2 * q + 1][i] = wb * (1.f / (sb + 1e-16f));
        __syncthreads();
        // ---- padded 8-wide gather batches: (h, lane) layout ----
        int degP = (deg + 7) & ~7;
        float acc0 = 0.f, acc1 = 0.f, acc2 = 0.f, acc3 = 0.f;
        for (int j = 0; j < degP; j += 8) {
            int4   t0 = *reinterpret_cast<const int4*>(&sS[j]);
            int4   t1 = *reinterpret_cast<const int4*>(&sS[j + 4]);
            float4 a0 = *reinterpret_cast<const float4*>(&sA[h][j]);
            float4 a1 = *reinterpret_cast<const float4*>(&sA[h][j + 4]);
            acc0 = fmaf(a0.x, x[t0.x * 32 + lane], acc0);
            acc1 = fmaf(a0.y, x[t0.y * 32 + lane], acc1);
            acc2 = fmaf(a0.z, x[t0.z * 32 + lane], acc2);
            acc3 = fmaf(a0.w, x[t0.w * 32 + lane], acc3);
            acc0 = fmaf(a1.x, x[t1.x * 32 + lane], acc0);
            acc1 = fmaf(a1.y, x[t1.y * 32 + lane], acc1);
            acc2 = fmaf(a1.z, x[t1.z * 32 + lane], acc2);
            acc3 = fmaf(a1.w, x[t1.w * 32 + lane], acc3);
        }
        acc = (acc0 + acc1) + (acc2 + acc3);
    } else {
        // generic fallback (recompute from global) — correct for any degree
        float adn = adst[node * 8 + h];
        float m = -1e30f;
        for (int i = lane; i < deg; i += 32) {
            int s = csr_src[beg + i];
            float e = asrc[s * 8 + h] + adn;
            e = fmaxf(e, NEG * e);
            m = fmaxf(m, e);
        }
#pragma unroll
        for (int off = 16; off; off >>= 1) m = fmaxf(m, __shfl_xor(m, off, 32));
        float dsum = 0.f;
        for (int i = lane; i < deg; i += 32) {
            int s = csr_src[beg + i];
            float e = asrc[s * 8 + h] + adn;
            e = fmaxf(e, NEG * e);
            dsum += __expf(e - m);
        }
#pragma unroll
        for (int off = 16; off; off >>= 1) dsum += __shfl_xor(dsum, off, 32);
        float inv = 1.f / (dsum + 1e-16f);
        for (int i = 0; i < deg; ++i) {
            int s = csr_src[beg + i];
            float e = asrc[s * 8 + h] + adn;
            e = fmaxf(e, NEG * e);
            acc = fmaf(__expf(e - m) * inv, x[s * 32 + lane], acc);
        }
    }
    AGG[(size_t)node * F1 + tid] = acc;   // coalesced 1KB write
}

// ---------------- batched MLP: x2 = relu(AGG @ blockdiag(W1) + b1); xh2 = x2 @ W2; alpha2 dots ----------------
// 16 nodes per block, 256 thr. Weights register-resident, AGG/x2 tiles in LDS.
__global__ __launch_bounds__(256) void mlp(
    const float* __restrict__ AGG, const float* __restrict__ W1, const float* __restrict__ b1,
    const float* __restrict__ W2, const float* __restrict__ as2, const float* __restrict__ ad2,
    float* __restrict__ xh2, float* __restrict__ asrc2, float* __restrict__ adst2, int N) {
    __shared__ float sT[NPB][F1];        // 16 KB: AGG tile, then reused as x2 tile
    __shared__ float spart[NPB][8][32];  // 16 KB
    int tid = threadIdx.x;
    int h = tid >> 5, c = tid & 31;      // h = head (phase 1) = k-group (phase 2)
    int base = blockIdx.x * NPB;

    // stage AGG tile (float4 coalesced)
    for (int i = tid; i < NPB * (F1 / 4); i += 256) {
        int n = i >> 6, j = i & 63;
        float4 v = (base + n < N) ? reinterpret_cast<const float4*>(AGG)[(size_t)(base + n) * 64 + j]
                                  : make_float4(0.f, 0.f, 0.f, 0.f);
        reinterpret_cast<float4*>(&sT[n][0])[j] = v;
    }
    // W1 column for output col tid -> registers
    float w1r[32];
#pragma unroll
    for (int d = 0; d < 32; ++d) w1r[d] = W1[d * F1 + tid];
    float bb = b1[tid];
    __syncthreads();

    // phase 1: x2[n, tid] for 16 nodes (LDS broadcast reads within head-group)
    float x2r[NPB];
#pragma unroll
    for (int n = 0; n < NPB; ++n) {
        float v = 0.f;
#pragma unroll
        for (int j = 0; j < 8; ++j) {
            float4 a4 = *reinterpret_cast<const float4*>(&sT[n][h * 32 + 4 * j]);
            v = fmaf(a4.x, w1r[4 * j],     v);
            v = fmaf(a4.y, w1r[4 * j + 1], v);
            v = fmaf(a4.z, w1r[4 * j + 2], v);
            v = fmaf(a4.w, w1r[4 * j + 3], v);
        }
        x2r[n] = fmaxf(v + bb, 0.f);
    }
    __syncthreads();   // done reading AGG tile
#pragma unroll
    for (int n = 0; n < NPB; ++n) sT[n][tid] = x2r[n];
    // W2 rows h*32..h*32+31, col c -> registers
    float w2r[32];
#pragma unroll
    for (int k2 = 0; k2 < 32; ++k2) w2r[k2] = W2[(h * 32 + k2) * 32 + c];
    __syncthreads();

    // phase 2: partial dot over k-group h
#pragma unroll
    for (int n = 0; n < NPB; ++n) {
        float p = 0.f;
#pragma unroll
        for (int j = 0; j < 8; ++j) {
            float4 a4 = *reinterpret_cast<const float4*>(&sT[n][h * 32 + 4 * j]);
            p = fmaf(a4.x, w2r[4 * j],     p);
            p = fmaf(a4.y, w2r[4 * j + 1], p);
            p = fmaf(a4.z, w2r[4 * j + 2], p);
            p = fmaf(a4.w, w2r[4 * j + 3], p);
        }
        spart[n][h][c] = p;
    }
    __syncthreads();

    // reduce 8 partials -> xh2, plus alpha2 dots
#pragma unroll
    for (int rep = 0; rep < 2; ++rep) {
        int n = (tid >> 5) + 8 * rep;
        float o = 0.f;
#pragma unroll
        for (int q = 0; q < 8; ++q) o += spart[n][q][c];
        int node = base + n;
        float ps = o * as2[c], pd = o * ad2[c];
#pragma unroll
        for (int off = 16; off; off >>= 1) { ps += __shfl_xor(ps, off, 32); pd += __shfl_xor(pd, off, 32); }
        if (node < N) {
            xh2[(size_t)node * 32 + c] = o;
            if (c == 0) { asrc2[node] = ps; adst2[node] = pd; }
        }
    }
}

// ---------------- layer-2 aggregation: 8 nodes/block, 32 lanes/node ----------------
// Zero-padded softmax cache -> full 8-wide gather batches; per-group LDS, no block barriers.
__global__ __launch_bounds__(256) void agg2(
    const float* __restrict__ xh2, const float* __restrict__ asrc2, const float* __restrict__ adst2,
    const int* __restrict__ rowptr, const int* __restrict__ csr_src,
    const float* __restrict__ b2, float* __restrict__ out, int N) {
    __shared__ float sA[8][DEGCAP];   // 2 KB
    __shared__ int   sS[8][DEGCAP];   // 2 KB
    int tid = threadIdx.x;
    int g = tid >> 5, lane = tid & 31;
    int node = blockIdx.x * 8 + g;
    if (node >= N) return;   // no barriers below — safe
    int beg = rowptr[node];
    int deg = rowptr[node + 1] - beg;
    float adn = adst2[node];
    float acc = 0.f;
    if (deg <= DEGCAP) {
        int i0 = lane, i1 = 32 + lane;
        int s0 = (i0 < deg) ? csr_src[beg + i0] : 0;
        int s1 = (i1 < deg) ? csr_src[beg + i1] : 0;
        sS[g][i0] = s0;
        sS[g][i1] = s1;
        float e0 = -1e30f, e1 = -1e30f;
        if (i0 < deg) { e0 = asrc2[s0] + adn; e0 = fmaxf(e0, NEG * e0); }
        if (i1 < deg) { e1 = asrc2[s1] + adn; e1 = fmaxf(e1, NEG * e1); }
        float m = fmaxf(e0, e1);
#pragma unroll
        for (int off = 16; off; off >>= 1) m = fmaxf(m, __shfl_xor(m, off, 32));
        float w0 = (i0 < deg) ? __expf(e0 - m) : 0.f;
        float w1 = (i1 < deg) ? __expf(e1 - m) : 0.f;
        sA[g][i0] = w0;           // unconditional: 0 beyond deg
        sA[g][i1] = w1;
        float dsum = w0 + w1;
#pragma unroll
        for (int off = 16; off; off >>= 1) dsum += __shfl_xor(dsum, off, 32);
        float inv = 1.f / (dsum + 1e-16f);
        // group reads only its own writes — wave-coherent, no barrier
        int degP = (deg + 7) & ~7;
        float acc0 = 0.f, acc1 = 0.f, acc2 = 0.f, acc3 = 0.f;
        for (int i = 0; i < degP; i += 8) {
            int4   t0 = *reinterpret_cast<const int4*>(&sS[g][i]);
            int4   t1 = *reinterpret_cast<const int4*>(&sS[g][i + 4]);
            float4 a0 = *reinterpret_cast<const float4*>(&sA[g][i]);
            float4 a1 = *reinterpret_cast<const float4*>(&sA[g][i + 4]);
            acc0 = fmaf(a0.x, xh2[t0.x * 32 + lane], acc0);
            acc1 = fmaf(a0.y, xh2[t0.y * 32 + lane], acc1);
            acc2 = fmaf(a0.z, xh2[t0.z * 32 + lane], acc2);
            acc3 = fmaf(a0.w, xh2[t0.w * 32 + lane], acc3);
            acc0 = fmaf(a1.x, xh2[t1.x * 32 + lane], acc0);
            acc1 = fmaf(a1.y, xh2[t1.y * 32 + lane], acc1);
            acc2 = fmaf(a1.z, xh2[t1.z * 32 + lane], acc2);
            acc3 = fmaf(a1.w, xh2[t1.w * 32 + lane], acc3);
        }
        acc = ((acc0 + acc1) + (acc2 + acc3)) * inv;
    } else {
        float m = -1e30f;
        for (int i = lane; i < deg; i += 32) {
            int s = csr_src[beg + i];
            float e = asrc2[s] + adn;
            e = fmaxf(e, NEG * e);
            m = fmaxf(m, e);
        }
#pragma unroll
        for (int off = 16; off; off >>= 1) m = fmaxf(m, __shfl_xor(m, off, 32));
        float dsum = 0.f;
        for (int i = lane; i < deg; i += 32) {
            int s = csr_src[beg + i];
            float e = asrc2[s] + adn;
            e = fmaxf(e, NEG * e);
            dsum += __expf(e - m);
        }
#pragma unroll
        for (int off = 16; off; off >>= 1) dsum += __shfl_xor(dsum, off, 32);
        float inv = 1.f / (dsum + 1e-16f);
        for (int i = 0; i < deg; ++i) {
            int s = csr_src[beg + i];
            float e = asrc2[s] + adn;
            e = fmaxf(e, NEG * e);
            acc = fmaf(__expf(e - m) * inv, xh2[s * 32 + lane], acc);
        }
    }
    out[node * 32 + lane] = acc + b2[lane];
}

extern "C" void kernel_launch(void* const* d_in, const int* in_sizes, int n_in,
                              void* d_out, int out_size, void* d_ws, size_t ws_size,
                              hipStream_t stream) {
    const float* features = (const float*)d_in[0];
    const int*   edge_idx = (const int*)d_in[1];
    const float* W1       = (const float*)d_in[2];
    const float* att_src1 = (const float*)d_in[3];
    const float* att_dst1 = (const float*)d_in[4];
    const float* b1       = (const float*)d_in[5];
    const float* W2       = (const float*)d_in[6];
    const float* att_src2 = (const float*)d_in[7];
    const float* att_dst2 = (const float*)d_in[8];
    const float* b2       = (const float*)d_in[9];
    float* out = (float*)d_out;

    const int N = in_sizes[0] / 32;          // 20000
    const int E = in_sizes[1] / 2;           // 320000
    const int Etot = E + N;
    const int nb = (N + 255) / 256;          // 79 scan blocks (<=128 assumed)
    const int CB = 625;                      // count blocks in fused kernel
    const int AB = (N + 31) / 32;            // alpha blocks
    const int* src_in = edge_idx;
    const int* dst_in = edge_idx + E;

    // workspace layout
    float* AGG   = (float*)d_ws;             // N*256 (20 MB)
    float* asrc1 = AGG + (size_t)N * F1;     // N*8
    float* adst1 = asrc1 + (size_t)N * 8;    // N*8
    float* xh2   = adst1 + (size_t)N * 8;    // N*32
    float* asrc2 = xh2 + (size_t)N * 32;     // N
    float* adst2 = asrc2 + N;                // N
    int* rowptr  = (int*)(adst2 + N);        // N+1
    int* cursor  = rowptr + (N + 1);         // N
    int* counts  = cursor + N;               // N
    int* bsum    = counts + N;               // 128
    int* csr_src = bsum + 128;               // Etot

    // CSR count (fused with layer-1 alpha computation)
    hipMemsetAsync(counts, 0, (size_t)N * sizeof(int), stream);
    count_alpha<<<CB + AB, 256, 0, stream>>>(dst_in, E, N, counts, CB,
                                             features, W1, att_src1, att_dst1, asrc1, adst1);
    scan_blk<<<nb, 256, 0, stream>>>(counts, N, bsum);
    scan_add2<<<nb, 256, 0, stream>>>(counts, bsum, nb, N, rowptr, cursor);
    scatter_edges<<<(Etot + 255) / 256, 256, 0, stream>>>(src_in, dst_in, E, N, cursor, csr_src);

    // layer-1 aggregation (input space)
    agg1<<<N, 256, 0, stream>>>(features, asrc1, adst1, rowptr, csr_src, AGG, N);

    // batched MLP (W1 + ReLU + W2) + layer-2 alpha dots
    mlp<<<(N + NPB - 1) / NPB, 256, 0, stream>>>(AGG, W1, b1, W2, att_src2, att_dst2,
                                                 xh2, asrc2, adst2, N);

    // layer 2 aggregation
    agg2<<<(N + 7) / 8, 256, 0, stream>>>(xh2, asrc2, adst2, rowptr, csr_src, b2, out, N);
}